// Round 9
// baseline (298.384 us; speedup 1.0000x reference)
//
#include <hip/hip_runtime.h>
#include <hip/hip_bf16.h>
#include <stdint.h>

#define SEQ 2048
#define DIM 64
#define NH  64          // B*H heads
#define KT  32          // keys per tile
#define NT  (SEQ / KT)  // 64 tiles per head
#define RAWK_BYTES 8192  // fp32 K tile
#define FRAG_BYTES 12288 // K hi/lo f16 (8KB) + V bf16 (4KB)
#define KF_BYTES   8192

typedef __attribute__((ext_vector_type(8)))  short    bf16x8;
typedef __attribute__((ext_vector_type(8)))  _Float16 f16x8;
typedef __attribute__((ext_vector_type(8)))  float    f32x8;
typedef __attribute__((ext_vector_type(16))) float    f32x16;
typedef unsigned int u32;

#if __has_builtin(__builtin_amdgcn_exp2f)
#define EXP2(x) __builtin_amdgcn_exp2f(x)
#else
#define EXP2(x) exp2f(x)
#endif

// key permutation: slot s in the 32-key tile holds key phi(s) (softmax is
// permutation-invariant over keys; K rows and V k-index use the same phi)
__device__ __forceinline__ int phi(int s) {
    int h = (s >> 2) & 1, b = s >> 3, i = s & 3;
    return 8 * h + 4 * b + i + (b >= 2 ? 8 : 0);
}

// 512 threads: waves 0-3 = consumers (64 q rows each -> each K/V fragment
// LDS read feeds 2 MFMAs, halving DS-pipe load vs 32-row layout),
// waves 4-7 = producers (stage K via glds, load V to regs, convert).
// Single barrier per tile; rawK and frag both 2-deep (40KB LDS total ->
// up to 4 blocks/CU resident for barrier/tail overlap).
__global__ __launch_bounds__(512, 4) void attn_fused(
    const float* __restrict__ Q, const float* __restrict__ K,
    const float* __restrict__ V, float* __restrict__ O)
{
    __shared__ __align__(16) char rawK[2][RAWK_BYTES];  // fp32 K staging
    __shared__ __align__(16) char frag[2][FRAG_BYTES];  // MFMA frag blobs

    const int tid  = threadIdx.x;
    const int wave = tid >> 6, lane = tid & 63;
    const int h = lane >> 5, col = lane & 31;

    // XCD swizzle: all 8 q-blocks of a head land on the same XCD (bijective,
    // 512 blocks round-robin over 8 XCDs -> K/V hit local L2)
    const int bid  = blockIdx.x;
    const int head = (bid & 7) * 8 + ((bid >> 3) & 7);
    const size_t base = (size_t)head * SEQ * DIM;

    if (wave < 4) {
        // ======================= CONSUMER =======================
        const int qw = (bid >> 6) * 256 + wave * 64;   // 64 q rows per wave

        // Q B-frags f16, log2e folded in: B[k=c*16+8h+j][n=col], 2 q-halves
        f16x8 qf[2][4];
        #pragma unroll
        for (int qt = 0; qt < 2; ++qt) {
            const float* qr = Q + base + (size_t)(qw + qt * 32 + col) * DIM;
            #pragma unroll
            for (int c = 0; c < 4; ++c)
                #pragma unroll
                for (int j = 0; j < 8; ++j)
                    qf[qt][c][j] = (_Float16)(qr[c * 16 + 8 * h + j] * 1.44269504088896f);
        }

        f32x16 z16;
        #pragma unroll
        for (int r = 0; r < 16; ++r) z16[r] = 0.f;
        f32x16 of[2][2];
        of[0][0] = z16; of[0][1] = z16; of[1][0] = z16; of[1][1] = z16;
        float l_own[2] = {0.f, 0.f};

        __builtin_amdgcn_s_barrier();   // P1: matches producer prologue barrier

        for (int kt = 0; kt < NT; ++kt) {
            // drain own ds reads, then join; frag[kt&1] converted last iter;
            // this barrier also licenses producers to overwrite frag[kt&1]
            // only AFTER we re-join at kt+1 (reads drained by then).
            asm volatile("s_waitcnt lgkmcnt(0)" ::: "memory");
            __builtin_amdgcn_s_barrier();
            __builtin_amdgcn_sched_barrier(0);
            const char* cur = frag[kt & 1];

            // S'^T[slot][q] = K.Q^T (log2 units), 2-term split precision;
            // each kh/kl LDS read feeds 2 MFMAs (both q-halves)
            f32x16 s[2]; s[0] = z16; s[1] = z16;
            __builtin_amdgcn_s_setprio(1);
            #pragma unroll
            for (int c = 0; c < 4; ++c) {
                f16x8 kh = *(const f16x8*)(cur + (c * 2 + 0) * 1024 + lane * 16);
                f16x8 kl = *(const f16x8*)(cur + (c * 2 + 1) * 1024 + lane * 16);
                s[0] = __builtin_amdgcn_mfma_f32_32x32x16_f16(kh, qf[0][c], s[0], 0, 0, 0);
                s[0] = __builtin_amdgcn_mfma_f32_32x32x16_f16(kl, qf[0][c], s[0], 0, 0, 0);
                s[1] = __builtin_amdgcn_mfma_f32_32x32x16_f16(kh, qf[1][c], s[1], 0, 0, 0);
                s[1] = __builtin_amdgcn_mfma_f32_32x32x16_f16(kl, qf[1][c], s[1], 0, 0, 0);
            }
            __builtin_amdgcn_s_setprio(0);

            // exp2, tree row-sum, pack to bf16; cross-half exchange via
            // v_permlane32_swap_b32
            bf16x8 pfrag[2][2];
            #pragma unroll
            for (int qt = 0; qt < 2; ++qt) {
                float p[16];
                #pragma unroll
                for (int r = 0; r < 16; ++r) p[r] = EXP2(s[qt][r]);
                float t0 = (p[0] + p[1]) + (p[2] + p[3]);
                float t1 = (p[4] + p[5]) + (p[6] + p[7]);
                float t2 = (p[8] + p[9]) + (p[10] + p[11]);
                float t3 = (p[12] + p[13]) + (p[14] + p[15]);
                l_own[qt] += (t0 + t1) + (t2 + t3);
                u32 pk[8];
                #pragma unroll
                for (int m = 0; m < 8; ++m) {
                    __hip_bfloat162 b2 = __float22bfloat162_rn(make_float2(p[2 * m], p[2 * m + 1]));
                    __builtin_memcpy(&pk[m], &b2, 4);
                }
                #pragma unroll
                for (int c = 0; c < 2; ++c) {
                    u32 a0 = pk[4 * c + 0], b0 = pk[4 * c + 2];
                    u32 a1 = pk[4 * c + 1], b1 = pk[4 * c + 3];
                    asm volatile("v_permlane32_swap_b32 %0, %1" : "+v"(a0), "+v"(b0));
                    asm volatile("v_permlane32_swap_b32 %0, %1" : "+v"(a1), "+v"(b1));
                    union { u32 w[4]; bf16x8 v; } fr;
                    fr.w[0] = a0; fr.w[1] = a1; fr.w[2] = b0; fr.w[3] = b1;
                    pfrag[qt][c] = fr.v;
                }
            }

            // O[q][d] += P.V; each vf LDS read feeds 2 MFMAs (both q-halves)
            __builtin_amdgcn_s_setprio(1);
            #pragma unroll
            for (int f = 0; f < 2; ++f)
                #pragma unroll
                for (int c = 0; c < 2; ++c) {
                    bf16x8 vf = *(const bf16x8*)(cur + KF_BYTES + (f * 2 + c) * 1024 + lane * 16);
                    of[0][f] = __builtin_amdgcn_mfma_f32_32x32x16_bf16(pfrag[0][c], vf, of[0][f], 0, 0, 0);
                    of[1][f] = __builtin_amdgcn_mfma_f32_32x32x16_bf16(pfrag[1][c], vf, of[1][f], 0, 0, 0);
                }
            __builtin_amdgcn_s_setprio(0);
        }

        // Epilogue: O /= l
        float* op = O + base;
        #pragma unroll
        for (int qt = 0; qt < 2; ++qt) {
            float lall = l_own[qt] + __shfl_xor(l_own[qt], 32);  // both halves of q=col
            float inv = 1.0f / lall;
            #pragma unroll
            for (int r = 0; r < 16; ++r) {
                int qrow = (r & 3) + 8 * (r >> 2) + 4 * h;
                float iq = __shfl(inv, qrow);
                op[(size_t)(qw + qt * 32 + qrow) * DIM + col]      = of[qt][0][r] * iq;
                op[(size_t)(qw + qt * 32 + qrow) * DIM + 32 + col] = of[qt][1][r] * iq;
            }
        }
    } else {
        // ======================= PRODUCER =======================
        const int pw = wave - 4;            // 0..3
        const float* Kh = K + base;
        const float* Vh = V + base;

        // V role: (fv,cv) per producer wave; 8 column-strided scalars
        const int fv = pw >> 1, cv = pw & 1;
        int vrow[8];
        #pragma unroll
        for (int j = 0; j < 8; ++j) vrow[j] = phi(16 * cv + 8 * h + j);

        // K staging: 2 glds per lane (512 chunks over 256 producer lanes).
        // Source chunk-swizzled (pos = k ^ (row&7)) so convert's row-major
        // 32B reads are bank-conflict-free; LDS dest linear (glds rule).
        auto stageK = [&](int kt, char* dst) {
            const char* g = (const char*)(Kh + (size_t)kt * (KT * DIM));
            #pragma unroll
            for (int i = 0; i < 2; ++i) {
                const int P  = pw * 128 + i * 64 + lane;
                const int sk = (P & ~15) | ((P & 15) ^ ((P >> 4) & 7));
                char* d = dst + (size_t)(pw * 128 + i * 64) * 16;  // wave-uniform
                __builtin_amdgcn_global_load_lds(
                    (const __attribute__((address_space(1))) u32*)(g + (size_t)sk * 16),
                    (__attribute__((address_space(3))) u32*)d, 16, 0, 0);
            }
        };
        auto loadV = [&](int kt) -> f32x8 {
            const float* vp = Vh + (size_t)kt * (KT * DIM) + fv * 32 + col;
            f32x8 r;
            #pragma unroll
            for (int j = 0; j < 8; ++j) r[j] = vp[vrow[j] * DIM];
            return r;
        };
        // rawK + V regs -> frag blob:
        //   K: [4c x {hi,lo} x 64lane x 8 f16]   V: [2f x 2c x 64lane x 8 bf16]
        auto convert = [&](const char* rk_, char* fr, f32x8 vv) {
            const int r = phi(col);
            const int kk = 4 * pw + 2 * h;
            const float4* rk4 = (const float4*)rk_;
            float4 a = rk4[r * 16 + ((kk    ) ^ (r & 7))];
            float4 b = rk4[r * 16 + ((kk + 1) ^ (r & 7))];
            float x[8] = {a.x, a.y, a.z, a.w, b.x, b.y, b.z, b.w};
            f16x8 hi, lo;
            #pragma unroll
            for (int j = 0; j < 8; ++j) {
                _Float16 xh = (_Float16)x[j];
                hi[j] = xh;
                lo[j] = (_Float16)(x[j] - (float)xh);
            }
            *(f16x8*)(fr + (pw * 2 + 0) * 1024 + lane * 16) = hi;
            *(f16x8*)(fr + (pw * 2 + 1) * 1024 + lane * 16) = lo;
            // packed RNE f32->bf16 (same rounding as manual f2bf)
            union { u32 w[4]; bf16x8 v; } uv;
            #pragma unroll
            for (int j = 0; j < 4; ++j) {
                __hip_bfloat162 b2 = __float22bfloat162_rn(make_float2(vv[2 * j], vv[2 * j + 1]));
                __builtin_memcpy(&uv.w[j], &b2, 4);
            }
            *(bf16x8*)(fr + KF_BYTES + (fv * 2 + cv) * 1024 + lane * 16) = uv.v;
        };

        // ---- prologue: tile 0 staged+converted; tile 1 in flight ----
        stageK(0, rawK[0]);
        f32x8 vv0 = loadV(0);
        asm volatile("s_waitcnt vmcnt(0)" ::: "memory");  // tile 0 loads landed
        __builtin_amdgcn_s_barrier();   // P1: all producers' glds landed
        convert(rawK[0], frag[0], vv0);
        stageK(1, rawK[1]);
        f32x8 vvE, vvO;                 // V regs for even/odd tiles
        vvO = loadV(1);

        for (int kt = 0; kt < NT; ++kt) {
            // vmcnt(0): tile kt+1's K-glds + V-loads (issued last iter)
            // landed; lgkm: my frag ds_writes drained. Then the shared
            // barrier publishes frag[kt&1] and licenses overwrites.
            asm volatile("s_waitcnt vmcnt(0) lgkmcnt(0)" ::: "memory");
            __builtin_amdgcn_s_barrier();
            __builtin_amdgcn_sched_barrier(0);

            const bool ld = (kt + 2 < NT);
            if (ld) stageK(kt + 2, rawK[kt & 1]);   // overwrites tile kt (converted @ kt-1)
            f32x8 vn;
            if (ld) vn = loadV(kt + 2);
            if (kt + 1 < NT)
                convert(rawK[(kt + 1) & 1], frag[(kt + 1) & 1],
                        ((kt + 1) & 1) ? vvO : vvE);
            if (ld) { if (kt & 1) vvO = vn; else vvE = vn; }  // (kt+2)&1 == kt&1

        }
    }
}

extern "C" void kernel_launch(void* const* d_in, const int* in_sizes, int n_in,
                              void* d_out, int out_size, void* d_ws, size_t ws_size,
                              hipStream_t stream) {
    const float* Q = (const float*)d_in[0];
    const float* K = (const float*)d_in[1];
    const float* V = (const float*)d_in[2];
    float* Out = (float*)d_out;
    (void)d_ws; (void)ws_size;

    attn_fused<<<dim3(NH * (SEQ / 256)), dim3(512), 0, stream>>>(Q, K, V, Out);
}

// Round 10
// 223.948 us; speedup vs baseline: 1.3324x; 1.3324x over previous
//
#include <hip/hip_runtime.h>
#include <hip/hip_bf16.h>
#include <stdint.h>

#define SEQ 2048
#define DIM 64
#define NH  64          // B*H heads
#define KT  32          // keys per tile
#define NT  (SEQ / KT)  // 64 tiles per head
#define NW  (NT / 2)    // 32 windows (2 tiles per barrier window)
#define FRAG_BYTES 12288 // K hi/lo f16 (8KB) + V bf16 (4KB)
#define KF_BYTES   8192

typedef __attribute__((ext_vector_type(8)))  short    bf16x8;
typedef __attribute__((ext_vector_type(8)))  _Float16 f16x8;
typedef __attribute__((ext_vector_type(8)))  float    f32x8;
typedef __attribute__((ext_vector_type(16))) float    f32x16;
typedef unsigned int u32;

#if __has_builtin(__builtin_amdgcn_exp2f)
#define EXP2(x) __builtin_amdgcn_exp2f(x)
#else
#define EXP2(x) exp2f(x)
#endif

// key permutation: slot s in the 32-key tile holds key phi(s) (softmax is
// permutation-invariant over keys; K rows and V k-index use the same phi)
__device__ __forceinline__ int phi(int s) {
    int h = (s >> 2) & 1, b = s >> 3, i = s & 3;
    return 8 * h + 4 * b + i + (b >= 2 ? 8 : 0);
}

// 768 threads: waves 0-7 = consumers (32 q rows each), waves 8-11 = producers.
// ONE barrier per 2-tile window (32 windows) -> barrier convoy halved vs r6.
// Producers load K (32B/lane contiguous) and V (8 scalars) straight to
// registers right after the barrier, convert both tiles into the frag blobs
// within the same window (producer-only latency, off the consumer path).
// frag is 4-deep: consumers read slots (2w)&3,(2w+1)&3 while producers
// write (2w+2)&3,(2w+3)&3 -- always disjoint; overwrites are licensed by
// the consumer's lgkm-drain + barrier one window later.
__global__ __launch_bounds__(768, 6) void attn_fused(
    const float* __restrict__ Q, const float* __restrict__ K,
    const float* __restrict__ V, float* __restrict__ O)
{
    __shared__ __align__(16) char frag[4][FRAG_BYTES];  // 48KB

    const int tid  = threadIdx.x;
    const int wave = tid >> 6, lane = tid & 63;
    const int h = lane >> 5, col = lane & 31;

    // XCD swizzle: all 8 q-blocks of a head land on the same XCD (bijective,
    // 512 blocks all co-resident at 2 blocks/CU -> K/V hit local L2)
    const int bid  = blockIdx.x;
    const int head = (bid & 7) * 8 + ((bid >> 3) & 7);
    const size_t base = (size_t)head * SEQ * DIM;

    if (wave < 8) {
        // ======================= CONSUMER =======================
        const int qw = (bid >> 6) * 256 + wave * 32;   // 32 q rows per wave

        // Q B-frags f16, log2e folded in: B[k=c*16+8h+j][n=col]
        f16x8 qf[4];
        {
            const float* qr = Q + base + (size_t)(qw + col) * DIM;
            #pragma unroll
            for (int c = 0; c < 4; ++c)
                #pragma unroll
                for (int j = 0; j < 8; ++j)
                    qf[c][j] = (_Float16)(qr[c * 16 + 8 * h + j] * 1.44269504088896f);
        }

        f32x16 z16;
        #pragma unroll
        for (int r = 0; r < 16; ++r) z16[r] = 0.f;
        f32x16 of[2];
        of[0] = z16; of[1] = z16;
        float l_own = 0.f;

        __builtin_amdgcn_s_barrier();   // P1: matches producer prologue barrier

        for (int w = 0; w < NW; ++w) {
            // drain own ds reads of the two slots producers overwrite next,
            // then join; frag[(2w)&3],frag[(2w+1)&3] converted last window
            asm volatile("s_waitcnt lgkmcnt(0)" ::: "memory");
            __builtin_amdgcn_s_barrier();
            __builtin_amdgcn_sched_barrier(0);

            #pragma unroll
            for (int tt = 0; tt < 2; ++tt) {
                const char* cur = frag[(2 * w + tt) & 3];

                // S'^T[slot][q] = K.Q^T (log2 units), 2-term split precision
                f32x16 s = z16;
                __builtin_amdgcn_s_setprio(1);
                #pragma unroll
                for (int c = 0; c < 4; ++c) {
                    f16x8 kh = *(const f16x8*)(cur + (c * 2 + 0) * 1024 + lane * 16);
                    f16x8 kl = *(const f16x8*)(cur + (c * 2 + 1) * 1024 + lane * 16);
                    s = __builtin_amdgcn_mfma_f32_32x32x16_f16(kh, qf[c], s, 0, 0, 0);
                    s = __builtin_amdgcn_mfma_f32_32x32x16_f16(kl, qf[c], s, 0, 0, 0);
                }
                __builtin_amdgcn_s_setprio(0);

                // exp2, tree row-sum, pack to bf16; cross-half exchange via
                // v_permlane32_swap_b32
                bf16x8 pfrag[2];
                {
                    float p[16];
                    #pragma unroll
                    for (int r = 0; r < 16; ++r) p[r] = EXP2(s[r]);
                    float t0 = (p[0] + p[1]) + (p[2] + p[3]);
                    float t1 = (p[4] + p[5]) + (p[6] + p[7]);
                    float t2 = (p[8] + p[9]) + (p[10] + p[11]);
                    float t3 = (p[12] + p[13]) + (p[14] + p[15]);
                    l_own += (t0 + t1) + (t2 + t3);
                    u32 pk[8];
                    #pragma unroll
                    for (int m = 0; m < 8; ++m) {
                        __hip_bfloat162 b2 = __float22bfloat162_rn(make_float2(p[2 * m], p[2 * m + 1]));
                        __builtin_memcpy(&pk[m], &b2, 4);
                    }
                    #pragma unroll
                    for (int c = 0; c < 2; ++c) {
                        u32 a0 = pk[4 * c + 0], b0 = pk[4 * c + 2];
                        u32 a1 = pk[4 * c + 1], b1 = pk[4 * c + 3];
                        asm volatile("v_permlane32_swap_b32 %0, %1" : "+v"(a0), "+v"(b0));
                        asm volatile("v_permlane32_swap_b32 %0, %1" : "+v"(a1), "+v"(b1));
                        union { u32 w[4]; bf16x8 v; } fr;
                        fr.w[0] = a0; fr.w[1] = a1; fr.w[2] = b0; fr.w[3] = b1;
                        pfrag[c] = fr.v;
                    }
                }

                // O[q][d] += P.V
                __builtin_amdgcn_s_setprio(1);
                #pragma unroll
                for (int f = 0; f < 2; ++f)
                    #pragma unroll
                    for (int c = 0; c < 2; ++c) {
                        bf16x8 vf = *(const bf16x8*)(cur + KF_BYTES + (f * 2 + c) * 1024 + lane * 16);
                        of[f] = __builtin_amdgcn_mfma_f32_32x32x16_bf16(pfrag[c], vf, of[f], 0, 0, 0);
                    }
                __builtin_amdgcn_s_setprio(0);
            }
        }

        // Epilogue: O /= l
        float* op = O + base;
        {
            float lall = l_own + __shfl_xor(l_own, 32);  // both halves of q=col
            float inv = 1.0f / lall;
            #pragma unroll
            for (int r = 0; r < 16; ++r) {
                int qrow = (r & 3) + 8 * (r >> 2) + 4 * h;
                float iq = __shfl(inv, qrow);
                op[(size_t)(qw + qrow) * DIM + col]      = of[0][r] * iq;
                op[(size_t)(qw + qrow) * DIM + 32 + col] = of[1][r] * iq;
            }
        }
    } else {
        // ======================= PRODUCER =======================
        const int pw = wave - 8;            // 0..3
        const float* Kh = K + base;
        const float* Vh = V + base;

        // K role: wave pw converts chunk c=pw -> lane reads
        // K[phi(col)][16*pw + 8*h .. +8] (32B contiguous)
        const float* kbase = Kh + (size_t)phi(col) * DIM + 16 * pw + 8 * h;
        // V role: (fv,cv) per producer wave; 8 column-strided scalars
        const int fv = pw >> 1, cv = pw & 1;
        int vrow[8];
        #pragma unroll
        for (int j = 0; j < 8; ++j) vrow[j] = phi(16 * cv + 8 * h + j);

        auto loadK = [&](int t, float4& a, float4& b) {
            const float* kp = kbase + (size_t)t * (KT * DIM);
            a = *(const float4*)kp;
            b = *(const float4*)(kp + 4);
        };
        auto loadV = [&](int t) -> f32x8 {
            const float* vp = Vh + (size_t)t * (KT * DIM) + fv * 32 + col;
            f32x8 r;
            #pragma unroll
            for (int j = 0; j < 8; ++j) r[j] = vp[vrow[j] * DIM];
            return r;
        };
        // K regs + V regs -> frag blob:
        //   K: [4c x {hi,lo} x 64lane x 8 f16]   V: [2f x 2c x 64lane x 8 bf16]
        auto convert = [&](char* fr, float4 a, float4 b, f32x8 vv) {
            float x[8] = {a.x, a.y, a.z, a.w, b.x, b.y, b.z, b.w};
            f16x8 hi, lo;
            #pragma unroll
            for (int j = 0; j < 8; ++j) {
                _Float16 xh = (_Float16)x[j];
                hi[j] = xh;
                lo[j] = (_Float16)(x[j] - (float)xh);
            }
            *(f16x8*)(fr + (pw * 2 + 0) * 1024 + lane * 16) = hi;
            *(f16x8*)(fr + (pw * 2 + 1) * 1024 + lane * 16) = lo;
            union { u32 w[4]; bf16x8 v; } uv;
            #pragma unroll
            for (int j = 0; j < 4; ++j) {
                __hip_bfloat162 b2 = __float22bfloat162_rn(make_float2(vv[2 * j], vv[2 * j + 1]));
                __builtin_memcpy(&uv.w[j], &b2, 4);
            }
            *(bf16x8*)(fr + KF_BYTES + (fv * 2 + cv) * 1024 + lane * 16) = uv.v;
        };

        // ---- prologue: tiles 0,1 -> frag[0],frag[1] ----
        float4 ka0, kb0, ka1, kb1;
        loadK(0, ka0, kb0);
        loadK(1, ka1, kb1);
        f32x8 vv0 = loadV(0);
        f32x8 vv1 = loadV(1);
        asm volatile("s_waitcnt vmcnt(0)" ::: "memory");
        convert(frag[0], ka0, kb0, vv0);
        convert(frag[1], ka1, kb1, vv1);
        asm volatile("s_waitcnt lgkmcnt(0)" ::: "memory");
        __builtin_amdgcn_s_barrier();   // P1: frag[0],frag[1] published

        for (int w = 0; w < NW; ++w) {
            __builtin_amdgcn_s_barrier();          // window barrier
            __builtin_amdgcn_sched_barrier(0);
            if (2 * w + 2 < NT) {
                // load tiles 2w+2, 2w+3 to regs; stall is producer-only
                loadK(2 * w + 2, ka0, kb0);
                loadK(2 * w + 3, ka1, kb1);
                vv0 = loadV(2 * w + 2);
                vv1 = loadV(2 * w + 3);
                asm volatile("s_waitcnt vmcnt(0)" ::: "memory");
                convert(frag[(2 * w + 2) & 3], ka0, kb0, vv0);
                convert(frag[(2 * w + 3) & 3], ka1, kb1, vv1);
            }
            // drain ds_writes before the next window barrier publishes them
            asm volatile("s_waitcnt lgkmcnt(0)" ::: "memory");
        }
    }
}

extern "C" void kernel_launch(void* const* d_in, const int* in_sizes, int n_in,
                              void* d_out, int out_size, void* d_ws, size_t ws_size,
                              hipStream_t stream) {
    const float* Q = (const float*)d_in[0];
    const float* K = (const float*)d_in[1];
    const float* V = (const float*)d_in[2];
    float* Out = (float*)d_out;
    (void)d_ws; (void)ws_size;

    attn_fused<<<dim3(NH * (SEQ / 256)), dim3(768), 0, stream>>>(Q, K, V, Out);
}